// Round 1
// baseline (12564.658 us; speedup 1.0000x reference)
//
#include <hip/hip_runtime.h>
#include <math.h>

#define NNODES 50000
#define NEDGES 250000
#define NREL   9
#define F_IN   128
#define HID    256
#define F_OUT  128

// conv1: relations 6,7,8 use norm='both'; conv2: all relations norm='both'
static const bool NORM1[NREL] = {false,false,false,false,false,false,true,true,true};

__device__ __forceinline__ void atomic_fadd(float* p, float v) {
    unsafeAtomicAdd(p, v);   // hardware global_atomic_add_f32 on gfx950
}

// ---------------- degree kernels ----------------
__global__ void count_deg_kernel(const int* __restrict__ src, const int* __restrict__ dst,
                                 int* __restrict__ degS, int* __restrict__ degD) {
    int i = blockIdx.x * blockDim.x + threadIdx.x;
    if (i >= NREL * NEDGES) return;
    int r = i / NEDGES;
    atomicAdd(&degS[r * NNODES + src[i]], 1);
    atomicAdd(&degD[r * NNODES + dst[i]], 1);
}

// in-place: int degree -> 1/sqrt(max(deg,1))
__global__ void finish_deg_kernel(float* __restrict__ dis) {
    int i = blockIdx.x * blockDim.x + threadIdx.x;
    if (i >= 2 * NREL * NNODES) return;
    int d = reinterpret_cast<const int*>(dis)[i];
    float fd = (float)(d < 1 ? 1 : d);
    dis[i] = 1.0f / sqrtf(fd);
}

// ---------------- scatter (edge aggregation) ----------------
// thread t handles one float4 of one edge: coalesced gather + 4 atomics
template<int F, bool NORM>
__global__ void scatter_kernel(const float* __restrict__ xin,
                               const int* __restrict__ src,
                               const int* __restrict__ dst,
                               const float* __restrict__ sscale,
                               float* __restrict__ agg) {
    constexpr int VPR = F / 4;
    int t = blockIdx.x * blockDim.x + threadIdx.x;
    if (t >= NEDGES * VPR) return;
    int e = t / VPR;
    int c = t % VPR;
    int s = src[e];
    int d = dst[e];
    float4 v = reinterpret_cast<const float4*>(xin)[(size_t)s * VPR + c];
    float sc = NORM ? sscale[s] : 1.0f;
    float* p = agg + (size_t)d * F + c * 4;
    atomic_fadd(p + 0, v.x * sc);
    atomic_fadd(p + 1, v.y * sc);
    atomic_fadd(p + 2, v.z * sc);
    atomic_fadd(p + 3, v.w * sc);
}

// ---------------- fp32 tiled GEMM: C[N,NN] += rowscale(A)[N,K] @ B[K,NN] ----------------
// 64x64 tile, TK=16, 256 threads, 4x4 per thread
template<int K, int NN>
__global__ __launch_bounds__(256) void gemm_acc(const float* __restrict__ A,
                                                const float* __restrict__ B,
                                                float* __restrict__ C,
                                                const float* __restrict__ rowscale) {
    __shared__ float As[16][64];
    __shared__ float Bs[16][64];
    int tid = threadIdx.x;
    int tx = tid & 15;   // N dir (4 cols each)
    int ty = tid >> 4;   // M dir (4 rows each)
    int m0 = blockIdx.x * 64;
    int n0 = blockIdx.y * 64;
    float acc[4][4] = {};

    for (int k0 = 0; k0 < K; k0 += 16) {
        // A tile: 64 rows x 16 k, one float4 per thread
        {
            int row = tid & 63;
            int kc4 = tid >> 6;         // 0..3
            int gr  = m0 + row;
            float4 av = make_float4(0.f, 0.f, 0.f, 0.f);
            if (gr < NNODES) {
                av = *reinterpret_cast<const float4*>(&A[(size_t)gr * K + k0 + kc4 * 4]);
                if (rowscale) {
                    float sc = rowscale[gr];
                    av.x *= sc; av.y *= sc; av.z *= sc; av.w *= sc;
                }
            }
            As[kc4 * 4 + 0][row] = av.x;
            As[kc4 * 4 + 1][row] = av.y;
            As[kc4 * 4 + 2][row] = av.z;
            As[kc4 * 4 + 3][row] = av.w;
        }
        // B tile: 16 k x 64 cols, one float4 per thread
        {
            int kk   = tid >> 4;        // 0..15
            int col4 = tid & 15;        // 0..15
            float4 bv = *reinterpret_cast<const float4*>(&B[(size_t)(k0 + kk) * NN + n0 + col4 * 4]);
            Bs[kk][col4 * 4 + 0] = bv.x;
            Bs[kk][col4 * 4 + 1] = bv.y;
            Bs[kk][col4 * 4 + 2] = bv.z;
            Bs[kk][col4 * 4 + 3] = bv.w;
        }
        __syncthreads();
        #pragma unroll
        for (int kk = 0; kk < 16; ++kk) {
            float4 a4 = *reinterpret_cast<const float4*>(&As[kk][ty * 4]);
            float4 b4 = *reinterpret_cast<const float4*>(&Bs[kk][tx * 4]);
            float a[4] = {a4.x, a4.y, a4.z, a4.w};
            float b[4] = {b4.x, b4.y, b4.z, b4.w};
            #pragma unroll
            for (int i = 0; i < 4; ++i)
                #pragma unroll
                for (int j = 0; j < 4; ++j)
                    acc[i][j] += a[i] * b[j];
        }
        __syncthreads();
    }
    #pragma unroll
    for (int i = 0; i < 4; ++i) {
        int gr = m0 + ty * 4 + i;
        if (gr >= NNODES) break;
        float* cp = C + (size_t)gr * NN + n0 + tx * 4;
        #pragma unroll
        for (int j = 0; j < 4; ++j) cp[j] += acc[i][j];
    }
}

// ---------------- bias + leaky relu ----------------
template<int F>
__global__ void bias_leaky_kernel(float* __restrict__ h, const float* __restrict__ b) {
    int i = blockIdx.x * blockDim.x + threadIdx.x;
    if (i >= NNODES * F) return;
    int j = i % F;
    float bs = 0.f;
    #pragma unroll
    for (int r = 0; r < NREL; ++r) bs += b[r * F + j];
    float v = h[i] + bs;
    h[i] = v > 0.f ? v : 0.01f * v;
}

extern "C" void kernel_launch(void* const* d_in, const int* in_sizes, int n_in,
                              void* d_out, int out_size, void* d_ws, size_t ws_size,
                              hipStream_t stream) {
    const float* x  = (const float*)d_in[0];
    const int*   src = (const int*)d_in[1];
    const int*   dst = (const int*)d_in[2];
    const float* W1 = (const float*)d_in[3];
    const float* b1 = (const float*)d_in[4];
    const float* W2 = (const float*)d_in[5];
    const float* b2 = (const float*)d_in[6];
    float* out = (float*)d_out;

    float* ws      = (float*)d_ws;
    float* dis_src = ws;                                   // [R, N]
    float* dis_dst = dis_src + (size_t)NREL * NNODES;      // [R, N]
    float* h1      = dis_dst + (size_t)NREL * NNODES;      // [N, HID]
    float* agg     = h1 + (size_t)NNODES * HID;            // [N, HID] (reused)

    // ---- degrees (shared by both layers) ----
    hipMemsetAsync(dis_src, 0, (size_t)2 * NREL * NNODES * sizeof(float), stream);
    {
        int tot = NREL * NEDGES;
        count_deg_kernel<<<(tot + 255) / 256, 256, 0, stream>>>(src, dst, (int*)dis_src, (int*)dis_dst);
    }
    {
        int tot = 2 * NREL * NNODES;
        finish_deg_kernel<<<(tot + 255) / 256, 256, 0, stream>>>(dis_src);
    }

    // ---- layer 1: h1 = sum_r rowscale(agg_r) @ W1_r ----
    hipMemsetAsync(h1, 0, (size_t)NNODES * HID * sizeof(float), stream);
    for (int r = 0; r < NREL; ++r) {
        hipMemsetAsync(agg, 0, (size_t)NNODES * F_IN * sizeof(float), stream);
        int tot = NEDGES * (F_IN / 4);
        if (NORM1[r])
            scatter_kernel<F_IN, true><<<(tot + 255) / 256, 256, 0, stream>>>(
                x, src + (size_t)r * NEDGES, dst + (size_t)r * NEDGES, dis_src + (size_t)r * NNODES, agg);
        else
            scatter_kernel<F_IN, false><<<(tot + 255) / 256, 256, 0, stream>>>(
                x, src + (size_t)r * NEDGES, dst + (size_t)r * NEDGES, nullptr, agg);
        dim3 g((NNODES + 63) / 64, HID / 64);
        gemm_acc<F_IN, HID><<<g, 256, 0, stream>>>(
            agg, W1 + (size_t)r * F_IN * HID, h1, NORM1[r] ? dis_dst + (size_t)r * NNODES : nullptr);
    }
    bias_leaky_kernel<HID><<<(NNODES * HID + 255) / 256, 256, 0, stream>>>(h1, b1);

    // ---- layer 2: out = sum_r rowscale(agg_r) @ W2_r ----
    hipMemsetAsync(out, 0, (size_t)NNODES * F_OUT * sizeof(float), stream);
    for (int r = 0; r < NREL; ++r) {
        hipMemsetAsync(agg, 0, (size_t)NNODES * HID * sizeof(float), stream);
        int tot = NEDGES * (HID / 4);
        scatter_kernel<HID, true><<<(tot + 255) / 256, 256, 0, stream>>>(
            h1, src + (size_t)r * NEDGES, dst + (size_t)r * NEDGES, dis_src + (size_t)r * NNODES, agg);
        dim3 g((NNODES + 63) / 64, F_OUT / 64);
        gemm_acc<HID, F_OUT><<<g, 256, 0, stream>>>(
            agg, W2 + (size_t)r * HID * F_OUT, out, dis_dst + (size_t)r * NNODES);
    }
    bias_leaky_kernel<F_OUT><<<(NNODES * F_OUT + 255) / 256, 256, 0, stream>>>(out, b2);
}

// Round 2
// 2000.840 us; speedup vs baseline: 6.2797x; 6.2797x over previous
//
#include <hip/hip_runtime.h>
#include <math.h>

#define NNODES 50000
#define NEDGES 250000
#define NREL   9
#define F_IN   128
#define HID    256
#define F_OUT  128
#define RN     (NREL * NNODES)
#define RE     (NREL * NEDGES)
#define SCAN_CHUNK 1024
#define NBLK   ((RN + SCAN_CHUNK - 1) / SCAN_CHUNK)   // 440

// conv1: relations 6,7,8 use norm='both'; conv2: all relations norm='both'
static const bool NORM1[NREL] = {false,false,false,false,false,false,true,true,true};

// ---------------- degree count ----------------
__global__ void count_deg_kernel(const int* __restrict__ src, const int* __restrict__ dst,
                                 int* __restrict__ degS, int* __restrict__ degD) {
    int i = blockIdx.x * blockDim.x + threadIdx.x;
    if (i >= RE) return;
    int r = i / NEDGES;
    atomicAdd(&degS[r * NNODES + src[i]], 1);
    atomicAdd(&degD[r * NNODES + dst[i]], 1);
}

// deg(int) -> 1/sqrt(max(deg,1)) over 2*R*N
__global__ void make_dis_kernel(const int* __restrict__ deg, float* __restrict__ dis) {
    int i = blockIdx.x * blockDim.x + threadIdx.x;
    if (i >= 2 * RN) return;
    int d = deg[i];
    dis[i] = rsqrtf((float)(d < 1 ? 1 : d));
}

// ---------------- exclusive scan over degD[RN] -> offsets[RN] ----------------
// A: per-1024-chunk sums
__global__ __launch_bounds__(256) void scanA_kernel(const int* __restrict__ deg, int* __restrict__ bsums) {
    __shared__ int sh[256];
    int t = threadIdx.x;
    int base = blockIdx.x * SCAN_CHUNK + t * 4;
    int s = 0;
    #pragma unroll
    for (int j = 0; j < 4; ++j) {
        int i = base + j;
        if (i < RN) s += deg[i];
    }
    sh[t] = s;
    __syncthreads();
    for (int off = 128; off > 0; off >>= 1) {
        if (t < off) sh[t] += sh[t + off];
        __syncthreads();
    }
    if (t == 0) bsums[blockIdx.x] = sh[0];
}

// B: single-block exclusive scan of bsums[NBLK]
__global__ __launch_bounds__(512) void scanB_kernel(int* __restrict__ bsums) {
    __shared__ int sh[512];
    int t = threadIdx.x;
    int v = (t < NBLK) ? bsums[t] : 0;
    sh[t] = v;
    __syncthreads();
    for (int off = 1; off < 512; off <<= 1) {
        int u = (t >= off) ? sh[t - off] : 0;
        __syncthreads();
        sh[t] += u;
        __syncthreads();
    }
    if (t < NBLK) bsums[t] = sh[t] - v;   // exclusive
}

// C: local exclusive scan + block offset -> offsets
__global__ __launch_bounds__(256) void scanC_kernel(const int* __restrict__ deg,
                                                    const int* __restrict__ bsums,
                                                    int* __restrict__ offs) {
    __shared__ int sh[256];
    int t = threadIdx.x;
    int base = blockIdx.x * SCAN_CHUNK + t * 4;
    int v[4];
    int s = 0;
    #pragma unroll
    for (int j = 0; j < 4; ++j) {
        int i = base + j;
        v[j] = (i < RN) ? deg[i] : 0;
        s += v[j];
    }
    sh[t] = s;
    __syncthreads();
    for (int off = 1; off < 256; off <<= 1) {
        int u = (t >= off) ? sh[t - off] : 0;
        __syncthreads();
        sh[t] += u;
        __syncthreads();
    }
    int p = bsums[blockIdx.x] + sh[t] - s;   // exclusive prefix for this thread's chunk
    #pragma unroll
    for (int j = 0; j < 4; ++j) {
        int i = base + j;
        if (i < RN) offs[i] = p;
        p += v[j];
    }
}

// ---------------- CSR fill: esrc sorted by (r, dst) ----------------
__global__ void fill_kernel(const int* __restrict__ src, const int* __restrict__ dst,
                            const int* __restrict__ offs, int* __restrict__ cursor,
                            int* __restrict__ esrc) {
    int i = blockIdx.x * blockDim.x + threadIdx.x;
    if (i >= RE) return;
    int r = i / NEDGES;
    int rn = r * NNODES + dst[i];
    int pos = offs[rn] + atomicAdd(&cursor[rn], 1);
    esrc[pos] = src[i];
}

// ---------------- gather aggregation: one (F/4)-lane group per dst node ----------------
template<int F, bool NORM>
__global__ __launch_bounds__(256) void gather_agg(const float* __restrict__ xin,
                                                  const int* __restrict__ esrc,
                                                  const int* __restrict__ offs,
                                                  const int* __restrict__ deg,
                                                  const float* __restrict__ dis_s,
                                                  const float* __restrict__ dis_d,
                                                  float* __restrict__ agg) {
    constexpr int LANES = F / 4;
    constexpr int NPB = 256 / LANES;
    int lane = threadIdx.x % LANES;
    int grp  = threadIdx.x / LANES;
    int n = blockIdx.x * NPB + grp;
    if (n >= NNODES) return;
    int st = offs[n];
    int en = st + deg[n];
    float4 acc = make_float4(0.f, 0.f, 0.f, 0.f);
    for (int k = st; k < en; ++k) {
        int s = esrc[k];
        float4 v = reinterpret_cast<const float4*>(xin)[(size_t)s * LANES + lane];
        float sc = NORM ? dis_s[s] : 1.0f;
        acc.x += v.x * sc; acc.y += v.y * sc; acc.z += v.z * sc; acc.w += v.w * sc;
    }
    if (NORM) {
        float dd = dis_d[n];
        acc.x *= dd; acc.y *= dd; acc.z *= dd; acc.w *= dd;
    }
    reinterpret_cast<float4*>(agg)[(size_t)n * LANES + lane] = acc;
}

// ---------------- fp32 tiled GEMM: C[N,NN] += A[N,K] @ B[K,NN] ----------------
template<int K, int NN>
__global__ __launch_bounds__(256) void gemm_acc(const float* __restrict__ A,
                                                const float* __restrict__ B,
                                                float* __restrict__ C) {
    __shared__ float As[16][64];
    __shared__ float Bs[16][64];
    int tid = threadIdx.x;
    int tx = tid & 15;   // N dir (4 cols each)
    int ty = tid >> 4;   // M dir (4 rows each)
    int m0 = blockIdx.x * 64;
    int n0 = blockIdx.y * 64;
    float acc[4][4] = {};

    for (int k0 = 0; k0 < K; k0 += 16) {
        {
            int row = tid & 63;
            int kc4 = tid >> 6;         // 0..3
            int gr  = m0 + row;
            float4 av = make_float4(0.f, 0.f, 0.f, 0.f);
            if (gr < NNODES)
                av = *reinterpret_cast<const float4*>(&A[(size_t)gr * K + k0 + kc4 * 4]);
            As[kc4 * 4 + 0][row] = av.x;
            As[kc4 * 4 + 1][row] = av.y;
            As[kc4 * 4 + 2][row] = av.z;
            As[kc4 * 4 + 3][row] = av.w;
        }
        {
            int kk   = tid >> 4;        // 0..15
            int col4 = tid & 15;        // 0..15
            float4 bv = *reinterpret_cast<const float4*>(&B[(size_t)(k0 + kk) * NN + n0 + col4 * 4]);
            Bs[kk][col4 * 4 + 0] = bv.x;
            Bs[kk][col4 * 4 + 1] = bv.y;
            Bs[kk][col4 * 4 + 2] = bv.z;
            Bs[kk][col4 * 4 + 3] = bv.w;
        }
        __syncthreads();
        #pragma unroll
        for (int kk = 0; kk < 16; ++kk) {
            float4 a4 = *reinterpret_cast<const float4*>(&As[kk][ty * 4]);
            float4 b4 = *reinterpret_cast<const float4*>(&Bs[kk][tx * 4]);
            float a[4] = {a4.x, a4.y, a4.z, a4.w};
            float b[4] = {b4.x, b4.y, b4.z, b4.w};
            #pragma unroll
            for (int i = 0; i < 4; ++i)
                #pragma unroll
                for (int j = 0; j < 4; ++j)
                    acc[i][j] += a[i] * b[j];
        }
        __syncthreads();
    }
    #pragma unroll
    for (int i = 0; i < 4; ++i) {
        int gr = m0 + ty * 4 + i;
        if (gr >= NNODES) break;
        float* cp = C + (size_t)gr * NN + n0 + tx * 4;
        #pragma unroll
        for (int j = 0; j < 4; ++j) cp[j] += acc[i][j];
    }
}

// ---------------- bias + leaky relu ----------------
template<int F>
__global__ void bias_leaky_kernel(float* __restrict__ h, const float* __restrict__ b) {
    int i = blockIdx.x * blockDim.x + threadIdx.x;
    if (i >= NNODES * F) return;
    int j = i % F;
    float bs = 0.f;
    #pragma unroll
    for (int r = 0; r < NREL; ++r) bs += b[r * F + j];
    float v = h[i] + bs;
    h[i] = v > 0.f ? v : 0.01f * v;
}

extern "C" void kernel_launch(void* const* d_in, const int* in_sizes, int n_in,
                              void* d_out, int out_size, void* d_ws, size_t ws_size,
                              hipStream_t stream) {
    const float* x   = (const float*)d_in[0];
    const int*   src = (const int*)d_in[1];
    const int*   dst = (const int*)d_in[2];
    const float* W1  = (const float*)d_in[3];
    const float* b1  = (const float*)d_in[4];
    const float* W2  = (const float*)d_in[5];
    const float* b2  = (const float*)d_in[6];
    float* out = (float*)d_out;

    // ---- workspace layout ----
    char* p = (char*)d_ws;
    int* degSD = (int*)p;            p += (size_t)2 * RN * sizeof(int);    // degS | degD
    float* disSD = (float*)p;        p += (size_t)2 * RN * sizeof(float);  // dis_src | dis_dst
    int* offs   = (int*)p;           p += (size_t)RN * sizeof(int);
    int* cursor = (int*)p;           p += (size_t)RN * sizeof(int);
    int* bsums  = (int*)p;           p += (size_t)1024 * sizeof(int);
    int* esrc   = (int*)p;           p += (size_t)RE * sizeof(int);
    float* h1   = (float*)p;         p += (size_t)NNODES * HID * sizeof(float);
    float* agg  = (float*)p;         // [N, HID] reused

    int* degS_i = degSD;
    int* degD_i = degSD + RN;
    float* dis_src = disSD;
    float* dis_dst = disSD + RN;

    // ---- degrees + CSR build (shared by both layers) ----
    hipMemsetAsync(degSD, 0, (size_t)2 * RN * sizeof(int), stream);
    count_deg_kernel<<<(RE + 255) / 256, 256, 0, stream>>>(src, dst, degS_i, degD_i);
    make_dis_kernel<<<(2 * RN + 255) / 256, 256, 0, stream>>>(degSD, disSD);
    scanA_kernel<<<NBLK, 256, 0, stream>>>(degD_i, bsums);
    scanB_kernel<<<1, 512, 0, stream>>>(bsums);
    scanC_kernel<<<NBLK, 256, 0, stream>>>(degD_i, bsums, offs);
    hipMemsetAsync(cursor, 0, (size_t)RN * sizeof(int), stream);
    fill_kernel<<<(RE + 255) / 256, 256, 0, stream>>>(src, dst, offs, cursor, esrc);

    // ---- layer 1: h1 = sum_r agg_r @ W1_r ----
    hipMemsetAsync(h1, 0, (size_t)NNODES * HID * sizeof(float), stream);
    for (int r = 0; r < NREL; ++r) {
        int grid = (NNODES + (256 / (F_IN / 4)) - 1) / (256 / (F_IN / 4));
        if (NORM1[r])
            gather_agg<F_IN, true><<<grid, 256, 0, stream>>>(
                x, esrc, offs + (size_t)r * NNODES, degD_i + (size_t)r * NNODES,
                dis_src + (size_t)r * NNODES, dis_dst + (size_t)r * NNODES, agg);
        else
            gather_agg<F_IN, false><<<grid, 256, 0, stream>>>(
                x, esrc, offs + (size_t)r * NNODES, degD_i + (size_t)r * NNODES,
                nullptr, nullptr, agg);
        dim3 g((NNODES + 63) / 64, HID / 64);
        gemm_acc<F_IN, HID><<<g, 256, 0, stream>>>(agg, W1 + (size_t)r * F_IN * HID, h1);
    }
    bias_leaky_kernel<HID><<<(NNODES * HID + 255) / 256, 256, 0, stream>>>(h1, b1);

    // ---- layer 2: out = sum_r agg_r @ W2_r ----
    hipMemsetAsync(out, 0, (size_t)NNODES * F_OUT * sizeof(float), stream);
    for (int r = 0; r < NREL; ++r) {
        int grid = (NNODES + (256 / (HID / 4)) - 1) / (256 / (HID / 4));
        gather_agg<HID, true><<<grid, 256, 0, stream>>>(
            h1, esrc, offs + (size_t)r * NNODES, degD_i + (size_t)r * NNODES,
            dis_src + (size_t)r * NNODES, dis_dst + (size_t)r * NNODES, agg);
        dim3 g((NNODES + 63) / 64, F_OUT / 64);
        gemm_acc<HID, F_OUT><<<g, 256, 0, stream>>>(agg, W2 + (size_t)r * HID * F_OUT, out);
    }
    bias_leaky_kernel<F_OUT><<<(NNODES * F_OUT + 255) / 256, 256, 0, stream>>>(out, b2);
}

// Round 3
// 808.152 us; speedup vs baseline: 15.5474x; 2.4758x over previous
//
#include <hip/hip_runtime.h>
#include <math.h>

#define NNODES 50000
#define NEDGES 250000
#define NREL   9
#define F_IN   128
#define HID    256
#define F_OUT  128
#define RN     (NREL * NNODES)
#define RE     (NREL * NEDGES)
#define MPAD   50048              // 391*128
#define K1     (NREL * F_IN)      // 1152
#define N1     HID                // 256
#define K2     HID                // 256
#define N2     (NREL * F_OUT)     // 1152
#define SCAN_CHUNK 1024
#define NBLK   ((RN + SCAN_CHUNK - 1) / SCAN_CHUNK)   // 440

typedef __attribute__((ext_vector_type(8))) short bf16x8;
typedef __attribute__((ext_vector_type(4))) float f32x4;

__device__ __forceinline__ float b2f(ushort u) { return __uint_as_float(((unsigned)u) << 16); }
__device__ __forceinline__ ushort f2b(float f) {
    unsigned u = __float_as_uint(f);
    unsigned r = (u + 0x7fffu + ((u >> 16) & 1u)) >> 16;
    return (ushort)r;
}
__device__ __forceinline__ void gload16(const void* g, void* l) {
    __builtin_amdgcn_global_load_lds((const __attribute__((address_space(1))) void*)g,
                                     (__attribute__((address_space(3))) void*)l, 16, 0, 0);
}

// ---------------- degree count ----------------
__global__ void count_deg_kernel(const int* __restrict__ src, const int* __restrict__ dst,
                                 int* __restrict__ degS, int* __restrict__ degD) {
    int i = blockIdx.x * blockDim.x + threadIdx.x;
    if (i >= RE) return;
    int r = i / NEDGES;
    atomicAdd(&degS[r * NNODES + src[i]], 1);
    atomicAdd(&degD[r * NNODES + dst[i]], 1);
}

__global__ void make_dis_kernel(const int* __restrict__ deg, float* __restrict__ dis) {
    int i = blockIdx.x * blockDim.x + threadIdx.x;
    if (i >= 2 * RN) return;
    int d = deg[i];
    dis[i] = rsqrtf((float)(d < 1 ? 1 : d));
}

// ---------------- exclusive scan over degD[RN] ----------------
__global__ __launch_bounds__(256) void scanA_kernel(const int* __restrict__ deg, int* __restrict__ bsums) {
    __shared__ int sh[256];
    int t = threadIdx.x;
    int base = blockIdx.x * SCAN_CHUNK + t * 4;
    int s = 0;
    #pragma unroll
    for (int j = 0; j < 4; ++j) { int i = base + j; if (i < RN) s += deg[i]; }
    sh[t] = s;
    __syncthreads();
    for (int off = 128; off > 0; off >>= 1) {
        if (t < off) sh[t] += sh[t + off];
        __syncthreads();
    }
    if (t == 0) bsums[blockIdx.x] = sh[0];
}

__global__ __launch_bounds__(512) void scanB_kernel(int* __restrict__ bsums) {
    __shared__ int sh[512];
    int t = threadIdx.x;
    int v = (t < NBLK) ? bsums[t] : 0;
    sh[t] = v;
    __syncthreads();
    for (int off = 1; off < 512; off <<= 1) {
        int u = (t >= off) ? sh[t - off] : 0;
        __syncthreads();
        sh[t] += u;
        __syncthreads();
    }
    if (t < NBLK) bsums[t] = sh[t] - v;
}

__global__ __launch_bounds__(256) void scanC_kernel(const int* __restrict__ deg,
                                                    const int* __restrict__ bsums,
                                                    int* __restrict__ offs) {
    __shared__ int sh[256];
    int t = threadIdx.x;
    int base = blockIdx.x * SCAN_CHUNK + t * 4;
    int v[4]; int s = 0;
    #pragma unroll
    for (int j = 0; j < 4; ++j) { int i = base + j; v[j] = (i < RN) ? deg[i] : 0; s += v[j]; }
    sh[t] = s;
    __syncthreads();
    for (int off = 1; off < 256; off <<= 1) {
        int u = (t >= off) ? sh[t - off] : 0;
        __syncthreads();
        sh[t] += u;
        __syncthreads();
    }
    int p = bsums[blockIdx.x] + sh[t] - s;
    #pragma unroll
    for (int j = 0; j < 4; ++j) { int i = base + j; if (i < RN) offs[i] = p; p += v[j]; }
}

// ---------------- CSR fill ----------------
__global__ void fill_kernel(const int* __restrict__ src, const int* __restrict__ dst,
                            const int* __restrict__ offs, int* __restrict__ cursor,
                            int* __restrict__ esrc) {
    int i = blockIdx.x * blockDim.x + threadIdx.x;
    if (i >= RE) return;
    int r = i / NEDGES;
    int rn = r * NNODES + dst[i];
    int pos = offs[rn] + atomicAdd(&cursor[rn], 1);
    esrc[pos] = src[i];
}

// ---------------- conversions ----------------
__global__ void to_bf16_kernel(const float* __restrict__ in, ushort* __restrict__ out, int n4) {
    int i = blockIdx.x * blockDim.x + threadIdx.x;
    if (i >= n4) return;
    float4 v = reinterpret_cast<const float4*>(in)[i];
    ushort4 o; o.x = f2b(v.x); o.y = f2b(v.y); o.z = f2b(v.z); o.w = f2b(v.w);
    reinterpret_cast<ushort4*>(out)[i] = o;
}

// W1 [R][F_IN][HID] -> W1t [HID][R*F_IN]
__global__ void w1t_kernel(const float* __restrict__ W1, ushort* __restrict__ W1t) {
    int idx = blockIdx.x * blockDim.x + threadIdx.x;
    if (idx >= NREL * F_IN * HID) return;
    int r = idx / (F_IN * HID);
    int k = (idx / HID) % F_IN;
    int j = idx % HID;
    W1t[(size_t)j * K1 + r * F_IN + k] = f2b(W1[idx]);
}

// W2 [R][HID][F_OUT] -> W2t [R*F_OUT][HID]
__global__ void w2t_kernel(const float* __restrict__ W2, ushort* __restrict__ W2t) {
    int idx = blockIdx.x * blockDim.x + threadIdx.x;
    if (idx >= NREL * HID * F_OUT) return;
    int r = idx / (HID * F_OUT);
    int k = (idx / F_OUT) % HID;
    int j = idx % F_OUT;
    W2t[(size_t)(r * F_OUT + j) * K2 + k] = f2b(W2[idx]);
}

__global__ void bias_sum_kernel(const float* __restrict__ b1, const float* __restrict__ b2,
                                float* __restrict__ bsum1, float* __restrict__ bsum2) {
    int i = threadIdx.x;
    if (i < HID)  { float s = 0; for (int r = 0; r < NREL; ++r) s += b1[r * HID + i];  bsum1[i] = s; }
    if (i < F_OUT){ float s = 0; for (int r = 0; r < NREL; ++r) s += b2[r * F_OUT + i]; bsum2[i] = s; }
}

// ---------------- layer-1 fused gather: AGG1[n][r*128+c] (bf16) ----------------
__global__ __launch_bounds__(256) void gather1_kernel(const ushort* __restrict__ x_bf,
                                                      const int* __restrict__ esrc,
                                                      const int* __restrict__ offs,
                                                      const int* __restrict__ degD,
                                                      const float* __restrict__ disS,
                                                      const float* __restrict__ disD,
                                                      ushort* __restrict__ buf) {
    int lane = threadIdx.x & 31, grp = threadIdx.x >> 5;
    int n = blockIdx.x * 8 + grp;
    if (n >= NNODES) return;
    for (int r = 0; r < NREL; ++r) {
        int rn = r * NNODES + n;
        int st = offs[rn], en = st + degD[rn];
        float ax = 0, ay = 0, az = 0, aw = 0;
        if (r < 6) {
            for (int k = st; k < en; ++k) {
                int s = esrc[k];
                ushort4 v = *reinterpret_cast<const ushort4*>(&x_bf[(size_t)s * F_IN + lane * 4]);
                ax += b2f(v.x); ay += b2f(v.y); az += b2f(v.z); aw += b2f(v.w);
            }
        } else {
            const float* ds = disS + (size_t)r * NNODES;
            for (int k = st; k < en; ++k) {
                int s = esrc[k];
                ushort4 v = *reinterpret_cast<const ushort4*>(&x_bf[(size_t)s * F_IN + lane * 4]);
                float sc = ds[s];
                ax += b2f(v.x) * sc; ay += b2f(v.y) * sc; az += b2f(v.z) * sc; aw += b2f(v.w) * sc;
            }
            float dd = disD[rn];
            ax *= dd; ay *= dd; az *= dd; aw *= dd;
        }
        ushort4 o; o.x = f2b(ax); o.y = f2b(ay); o.z = f2b(az); o.w = f2b(aw);
        *reinterpret_cast<ushort4*>(&buf[(size_t)n * K1 + r * F_IN + lane * 4]) = o;
    }
}

// ---------------- layer-2 fused gather (weight-first finish): out fp32 ----------------
__global__ __launch_bounds__(256) void gather2_kernel(const ushort* __restrict__ T,
                                                      const int* __restrict__ esrc,
                                                      const int* __restrict__ offs,
                                                      const int* __restrict__ degD,
                                                      const float* __restrict__ disS,
                                                      const float* __restrict__ disD,
                                                      const float* __restrict__ bsum2,
                                                      float* __restrict__ out) {
    int lane = threadIdx.x & 31, grp = threadIdx.x >> 5;
    int n = blockIdx.x * 8 + grp;
    if (n >= NNODES) return;
    float4 acc = *reinterpret_cast<const float4*>(&bsum2[lane * 4]);
    for (int r = 0; r < NREL; ++r) {
        int rn = r * NNODES + n;
        int st = offs[rn], en = st + degD[rn];
        const float* ds = disS + (size_t)r * NNODES;
        float ax = 0, ay = 0, az = 0, aw = 0;
        for (int k = st; k < en; ++k) {
            int s = esrc[k];
            ushort4 v = *reinterpret_cast<const ushort4*>(&T[(size_t)s * N2 + r * F_OUT + lane * 4]);
            float sc = ds[s];
            ax += b2f(v.x) * sc; ay += b2f(v.y) * sc; az += b2f(v.z) * sc; aw += b2f(v.w) * sc;
        }
        float dd = disD[rn];
        acc.x += ax * dd; acc.y += ay * dd; acc.z += az * dd; acc.w += aw * dd;
    }
    acc.x = acc.x > 0.f ? acc.x : 0.01f * acc.x;
    acc.y = acc.y > 0.f ? acc.y : 0.01f * acc.y;
    acc.z = acc.z > 0.f ? acc.z : 0.01f * acc.z;
    acc.w = acc.w > 0.f ? acc.w : 0.01f * acc.w;
    *reinterpret_cast<float4*>(&out[(size_t)n * F_OUT + lane * 4]) = acc;
}

// ---------------- bf16 MFMA GEMM: C[M][NOUT] = A[M][KDIM] @ Bt[NOUT][KDIM]^T ----------------
// 128x128 tile, BK=64, 4 waves (2x2 of 64x64), global_load_lds w/ pre-swizzled src,
// XOR-swizzled ds_read_b128 (conflict-free). EPI: bias+leaky. Output bf16.
template<int KDIM, int NOUT, bool EPI>
__global__ __launch_bounds__(256) void gemm_bf16(const ushort* __restrict__ A, int Astride,
                                                 const ushort* __restrict__ Bt, int Bstride,
                                                 ushort* __restrict__ C,
                                                 const float* __restrict__ bsum) {
    __shared__ ushort Al[128 * 64];
    __shared__ ushort Bl[128 * 64];
    const int tid = threadIdx.x;
    const int lane = tid & 63;
    const int w = tid >> 6;
    const int wm = w >> 1, wn = w & 1;
    const int m0 = blockIdx.x * 128, n0 = blockIdx.y * 128;

    // staging: wave w stages rows [w*32, w*32+32) of both tiles; 8 rows per gload.
    // LDS dest is linear; global src slot pre-swizzled: sl = (lane&7) ^ (lane>>3).
    const int r8 = lane >> 3;
    const int sl = (lane & 7) ^ r8;
    const char* Ab = (const char*)A + (size_t)(m0 + w * 32 + r8) * Astride + sl * 16;
    const char* Bb = (const char*)Bt + (size_t)(n0 + w * 32 + r8) * Bstride + sl * 16;

    f32x4 acc[4][4];
    #pragma unroll
    for (int i = 0; i < 4; ++i)
        #pragma unroll
        for (int j = 0; j < 4; ++j) acc[i][j] = (f32x4){0.f, 0.f, 0.f, 0.f};

    for (int kt = 0; kt < KDIM / 64; ++kt) {
        const size_t kb = (size_t)kt * 128;   // 64 bf16 = 128 bytes
        #pragma unroll
        for (int i = 0; i < 4; ++i) {
            gload16(Ab + (size_t)(i * 8) * Astride + kb, &Al[(w * 32 + i * 8) * 64]);
            gload16(Bb + (size_t)(i * 8) * Bstride + kb, &Bl[(w * 32 + i * 8) * 64]);
        }
        __syncthreads();
        bf16x8 a[2][4], b[2][4];
        #pragma unroll
        for (int ks = 0; ks < 2; ++ks) {
            #pragma unroll
            for (int m = 0; m < 4; ++m) {
                int row = wm * 64 + m * 16 + (lane & 15);
                int slot = (ks * 4 + (lane >> 4)) ^ (row & 7);
                a[ks][m] = *reinterpret_cast<const bf16x8*>(&Al[row * 64 + slot * 8]);
                int rowb = wn * 64 + m * 16 + (lane & 15);
                int slotb = (ks * 4 + (lane >> 4)) ^ (rowb & 7);
                b[ks][m] = *reinterpret_cast<const bf16x8*>(&Bl[rowb * 64 + slotb * 8]);
            }
        }
        #pragma unroll
        for (int ks = 0; ks < 2; ++ks)
            #pragma unroll
            for (int m = 0; m < 4; ++m)
                #pragma unroll
                for (int n = 0; n < 4; ++n)
                    acc[m][n] = __builtin_amdgcn_mfma_f32_16x16x32_bf16(a[ks][m], b[ks][n], acc[m][n], 0, 0, 0);
        __syncthreads();
    }
    // epilogue: C row = (lane>>4)*4+q, col = lane&15 within each 16x16 frag
    #pragma unroll
    for (int m = 0; m < 4; ++m) {
        int rbase = m0 + wm * 64 + m * 16 + (lane >> 4) * 4;
        #pragma unroll
        for (int n = 0; n < 4; ++n) {
            int col = n0 + wn * 64 + n * 16 + (lane & 15);
            float bb = EPI ? bsum[col] : 0.f;
            #pragma unroll
            for (int q = 0; q < 4; ++q) {
                int r = rbase + q;
                if (r < NNODES) {
                    float v = acc[m][n][q];
                    if (EPI) { v += bb; v = v > 0.f ? v : 0.01f * v; }
                    C[(size_t)r * NOUT + col] = f2b(v);
                }
            }
        }
    }
}

extern "C" void kernel_launch(void* const* d_in, const int* in_sizes, int n_in,
                              void* d_out, int out_size, void* d_ws, size_t ws_size,
                              hipStream_t stream) {
    const float* x   = (const float*)d_in[0];
    const int*   src = (const int*)d_in[1];
    const int*   dst = (const int*)d_in[2];
    const float* W1  = (const float*)d_in[3];
    const float* b1  = (const float*)d_in[4];
    const float* W2  = (const float*)d_in[5];
    const float* b2  = (const float*)d_in[6];
    float* out = (float*)d_out;

    // ---- workspace layout (all chunk sizes multiples of 16B) ----
    char* p = (char*)d_ws;
    int*    degSD = (int*)p;    p += (size_t)2 * RN * sizeof(int);
    float*  disSD = (float*)p;  p += (size_t)2 * RN * sizeof(float);
    int*    offs  = (int*)p;    p += (size_t)RN * sizeof(int);
    int*    cursor= (int*)p;    p += (size_t)RN * sizeof(int);
    int*    bsums = (int*)p;    p += (size_t)1024 * sizeof(int);
    float*  bsum1 = (float*)p;  p += (size_t)512 * sizeof(float);   // 256 used
    float*  bsum2 = (float*)p;  p += (size_t)512 * sizeof(float);   // 128 used
    int*    esrc  = (int*)p;    p += (size_t)RE * sizeof(int);
    ushort* x_bf  = (ushort*)p; p += (size_t)NNODES * F_IN * sizeof(ushort);
    ushort* W1t   = (ushort*)p; p += (size_t)N1 * K1 * sizeof(ushort);
    ushort* W2t   = (ushort*)p; p += (size_t)N2 * K2 * sizeof(ushort);
    ushort* h1_bf = (ushort*)p; p += (size_t)MPAD * HID * sizeof(ushort);
    ushort* buf   = (ushort*)p; // [MPAD][K1] bf16: AGG1, then T (115MB)

    int* degS_i = degSD;
    int* degD_i = degSD + RN;
    float* dis_src = disSD;
    float* dis_dst = disSD + RN;

    // ---- CSR build (shared by both layers) ----
    hipMemsetAsync(degSD, 0, (size_t)2 * RN * sizeof(int), stream);
    count_deg_kernel<<<(RE + 255) / 256, 256, 0, stream>>>(src, dst, degS_i, degD_i);
    make_dis_kernel<<<(2 * RN + 255) / 256, 256, 0, stream>>>(degSD, disSD);
    scanA_kernel<<<NBLK, 256, 0, stream>>>(degD_i, bsums);
    scanB_kernel<<<1, 512, 0, stream>>>(bsums);
    scanC_kernel<<<NBLK, 256, 0, stream>>>(degD_i, bsums, offs);
    hipMemsetAsync(cursor, 0, (size_t)RN * sizeof(int), stream);
    fill_kernel<<<(RE + 255) / 256, 256, 0, stream>>>(src, dst, offs, cursor, esrc);

    // ---- precompute: bf16 conversions ----
    to_bf16_kernel<<<(NNODES * F_IN / 4 + 255) / 256, 256, 0, stream>>>(x, x_bf, NNODES * F_IN / 4);
    w1t_kernel<<<(NREL * F_IN * HID + 255) / 256, 256, 0, stream>>>(W1, W1t);
    w2t_kernel<<<(NREL * HID * F_OUT + 255) / 256, 256, 0, stream>>>(W2, W2t);
    bias_sum_kernel<<<1, 256, 0, stream>>>(b1, b2, bsum1, bsum2);

    // ---- layer 1: gather (aggregate-first, stacked) then one GEMM ----
    gather1_kernel<<<(NNODES + 7) / 8, 256, 0, stream>>>(x_bf, esrc, offs, degD_i,
                                                         dis_src, dis_dst, buf);
    {
        dim3 g(MPAD / 128, N1 / 128);
        gemm_bf16<K1, N1, true><<<g, 256, 0, stream>>>(buf, K1 * 2, W1t, K1 * 2, h1_bf, bsum1);
    }

    // ---- layer 2: weight-first GEMM (T = h1 @ W2stack) then fused gather ----
    {
        dim3 g(MPAD / 128, N2 / 128);
        gemm_bf16<K2, N2, false><<<g, 256, 0, stream>>>(h1_bf, K2 * 2, W2t, K2 * 2, buf, nullptr);
    }
    gather2_kernel<<<(NNODES + 7) / 8, 256, 0, stream>>>(buf, esrc, offs, degD_i,
                                                         dis_src, dis_dst, bsum2, out);
}

// Round 4
// 568.365 us; speedup vs baseline: 22.1067x; 1.4219x over previous
//
#include <hip/hip_runtime.h>
#include <math.h>

#define NNODES 50000
#define NEDGES 250000
#define NREL   9
#define F_IN   128
#define HID    256
#define F_OUT  128
#define RN     (NREL * NNODES)
#define RE     (NREL * NEDGES)
#define MPAD   50048              // 391*128
#define K1     (NREL * F_IN)      // 1152
#define N1     HID                // 256
#define K2     HID                // 256
#define N2     (NREL * F_OUT)     // 1152
#define SCAN_CHUNK 1024
#define NBLK   ((RN + SCAN_CHUNK - 1) / SCAN_CHUNK)   // 440
#define RANGE  12500              // dst-range per histogram block
#define NRANGE 4                  // RANGE*NRANGE = NNODES
#define NCHUNK 8
#define CHUNKE (NEDGES / NCHUNK)  // 31250

typedef __attribute__((ext_vector_type(8))) short bf16x8;
typedef __attribute__((ext_vector_type(4))) float f32x4;

__device__ __forceinline__ float b2f(ushort u) { return __uint_as_float(((unsigned)u) << 16); }
__device__ __forceinline__ ushort f2b(float f) {
    unsigned u = __float_as_uint(f);
    unsigned r = (u + 0x7fffu + ((u >> 16) & 1u)) >> 16;
    return (ushort)r;
}
__device__ __forceinline__ void gload16(const void* g, void* l) {
    __builtin_amdgcn_global_load_lds((const __attribute__((address_space(1))) void*)g,
                                     (__attribute__((address_space(3))) void*)l, 16, 0, 0);
}

// ---------------- LDS-privatized histogram (no global atomics) ----------------
// block (chunk c, range rg, relation r): histogram idx values in [rg*RANGE, ...) of
// chunk c of relation r into LDS, write to cnt[c][r*N + range]
__global__ __launch_bounds__(256) void hist_kernel(const int* __restrict__ idx,
                                                   int* __restrict__ cnt) {
    __shared__ int h[RANGE];
    int c = blockIdx.x, rg = blockIdx.y, r = blockIdx.z;
    int lo = rg * RANGE;
    for (int i = threadIdx.x; i < RANGE; i += 256) h[i] = 0;
    __syncthreads();
    const int2* base = reinterpret_cast<const int2*>(idx + (size_t)r * NEDGES + (size_t)c * CHUNKE);
    for (int i = threadIdx.x; i < CHUNKE / 2; i += 256) {
        int2 v = base[i];
        int a = v.x - lo; if ((unsigned)a < RANGE) atomicAdd(&h[a], 1);
        int b = v.y - lo; if ((unsigned)b < RANGE) atomicAdd(&h[b], 1);
    }
    __syncthreads();
    int* outp = cnt + (size_t)c * RN + (size_t)r * NNODES + lo;
    for (int i = threadIdx.x; i < RANGE; i += 256) outp[i] = h[i];
}

// sum chunk histograms -> degD total + norm scales
__global__ void sumdis_kernel(const int* __restrict__ cnt_s, const int* __restrict__ cnt_d,
                              int* __restrict__ degD, float* __restrict__ disS,
                              float* __restrict__ disD) {
    int i = blockIdx.x * blockDim.x + threadIdx.x;
    if (i >= RN) return;
    int s = 0, d = 0;
    #pragma unroll
    for (int c = 0; c < NCHUNK; ++c) {
        s += cnt_s[(size_t)c * RN + i];
        d += cnt_d[(size_t)c * RN + i];
    }
    degD[i] = d;
    disS[i] = rsqrtf((float)(s < 1 ? 1 : s));
    disD[i] = rsqrtf((float)(d < 1 ? 1 : d));
}

// ---------------- exclusive scan over degD[RN] ----------------
__global__ __launch_bounds__(256) void scanA_kernel(const int* __restrict__ deg, int* __restrict__ bsums) {
    __shared__ int sh[256];
    int t = threadIdx.x;
    int base = blockIdx.x * SCAN_CHUNK + t * 4;
    int s = 0;
    #pragma unroll
    for (int j = 0; j < 4; ++j) { int i = base + j; if (i < RN) s += deg[i]; }
    sh[t] = s;
    __syncthreads();
    for (int off = 128; off > 0; off >>= 1) {
        if (t < off) sh[t] += sh[t + off];
        __syncthreads();
    }
    if (t == 0) bsums[blockIdx.x] = sh[0];
}

__global__ __launch_bounds__(512) void scanB_kernel(int* __restrict__ bsums) {
    __shared__ int sh[512];
    int t = threadIdx.x;
    int v = (t < NBLK) ? bsums[t] : 0;
    sh[t] = v;
    __syncthreads();
    for (int off = 1; off < 512; off <<= 1) {
        int u = (t >= off) ? sh[t - off] : 0;
        __syncthreads();
        sh[t] += u;
        __syncthreads();
    }
    if (t < NBLK) bsums[t] = sh[t] - v;
}

__global__ __launch_bounds__(256) void scanC_kernel(const int* __restrict__ deg,
                                                    const int* __restrict__ bsums,
                                                    int* __restrict__ offs) {
    __shared__ int sh[256];
    int t = threadIdx.x;
    int base = blockIdx.x * SCAN_CHUNK + t * 4;
    int v[4]; int s = 0;
    #pragma unroll
    for (int j = 0; j < 4; ++j) { int i = base + j; v[j] = (i < RN) ? deg[i] : 0; s += v[j]; }
    sh[t] = s;
    __syncthreads();
    for (int off = 1; off < 256; off <<= 1) {
        int u = (t >= off) ? sh[t - off] : 0;
        __syncthreads();
        sh[t] += u;
        __syncthreads();
    }
    int p = bsums[blockIdx.x] + sh[t] - s;
    #pragma unroll
    for (int j = 0; j < 4; ++j) { int i = base + j; if (i < RN) offs[i] = p; p += v[j]; }
}

// per-chunk cursor bases: cbase[c][i] = offs[i] + sum_{c'<c} cnt_d[c'][i]
__global__ void chunkbase_kernel(const int* __restrict__ cnt_d, const int* __restrict__ offs,
                                 int* __restrict__ cbase) {
    int i = blockIdx.x * blockDim.x + threadIdx.x;
    if (i >= RN) return;
    int p = offs[i];
    #pragma unroll
    for (int c = 0; c < NCHUNK; ++c) {
        cbase[(size_t)c * RN + i] = p;
        p += cnt_d[(size_t)c * RN + i];
    }
}

// ---------------- CSR fill with LDS cursors (no global atomics) ----------------
__global__ __launch_bounds__(256) void fill2_kernel(const int* __restrict__ src,
                                                    const int* __restrict__ dst,
                                                    const int* __restrict__ cbase,
                                                    int* __restrict__ esrc) {
    __shared__ int cur[RANGE];
    int c = blockIdx.x, rg = blockIdx.y, r = blockIdx.z;
    int lo = rg * RANGE;
    const int* cb = cbase + (size_t)c * RN + (size_t)r * NNODES + lo;
    for (int i = threadIdx.x; i < RANGE; i += 256) cur[i] = cb[i];
    __syncthreads();
    const int2* sb = reinterpret_cast<const int2*>(src + (size_t)r * NEDGES + (size_t)c * CHUNKE);
    const int2* db = reinterpret_cast<const int2*>(dst + (size_t)r * NEDGES + (size_t)c * CHUNKE);
    for (int i = threadIdx.x; i < CHUNKE / 2; i += 256) {
        int2 s2 = sb[i];
        int2 d2 = db[i];
        int a = d2.x - lo;
        if ((unsigned)a < RANGE) { int pos = atomicAdd(&cur[a], 1); esrc[pos] = s2.x; }
        int b = d2.y - lo;
        if ((unsigned)b < RANGE) { int pos = atomicAdd(&cur[b], 1); esrc[pos] = s2.y; }
    }
}

// ---------------- conversions ----------------
__global__ void to_bf16_kernel(const float* __restrict__ in, ushort* __restrict__ out, int n4) {
    int i = blockIdx.x * blockDim.x + threadIdx.x;
    if (i >= n4) return;
    float4 v = reinterpret_cast<const float4*>(in)[i];
    ushort4 o; o.x = f2b(v.x); o.y = f2b(v.y); o.z = f2b(v.z); o.w = f2b(v.w);
    reinterpret_cast<ushort4*>(out)[i] = o;
}

// W1 [R][F_IN][HID] -> W1t [HID][R*F_IN]
__global__ void w1t_kernel(const float* __restrict__ W1, ushort* __restrict__ W1t) {
    int idx = blockIdx.x * blockDim.x + threadIdx.x;
    if (idx >= NREL * F_IN * HID) return;
    int r = idx / (F_IN * HID);
    int k = (idx / HID) % F_IN;
    int j = idx % HID;
    W1t[(size_t)j * K1 + r * F_IN + k] = f2b(W1[idx]);
}

// W2 [R][HID][F_OUT] -> W2t [R*F_OUT][HID]
__global__ void w2t_kernel(const float* __restrict__ W2, ushort* __restrict__ W2t) {
    int idx = blockIdx.x * blockDim.x + threadIdx.x;
    if (idx >= NREL * HID * F_OUT) return;
    int r = idx / (HID * F_OUT);
    int k = (idx / F_OUT) % HID;
    int j = idx % F_OUT;
    W2t[(size_t)(r * F_OUT + j) * K2 + k] = f2b(W2[idx]);
}

__global__ void bias_sum_kernel(const float* __restrict__ b1, const float* __restrict__ b2,
                                float* __restrict__ bsum1, float* __restrict__ bsum2) {
    int i = threadIdx.x;
    if (i < HID)  { float s = 0; for (int r = 0; r < NREL; ++r) s += b1[r * HID + i];  bsum1[i] = s; }
    if (i < F_OUT){ float s = 0; for (int r = 0; r < NREL; ++r) s += b2[r * F_OUT + i]; bsum2[i] = s; }
}

// ---------------- layer-1 fused gather (4-way ILP): AGG1[n][r*128+c] bf16 ----------------
__global__ __launch_bounds__(256) void gather1_kernel(const ushort* __restrict__ x_bf,
                                                      const int* __restrict__ esrc,
                                                      const int* __restrict__ offs,
                                                      const int* __restrict__ degD,
                                                      const float* __restrict__ disS,
                                                      const float* __restrict__ disD,
                                                      ushort* __restrict__ buf) {
    int lane = threadIdx.x & 31, grp = threadIdx.x >> 5;
    int n = blockIdx.x * 8 + grp;
    if (n >= NNODES) return;
    const ushort* xb = x_bf + lane * 4;
    for (int r = 0; r < NREL; ++r) {
        int rn = r * NNODES + n;
        int st = offs[rn], en = st + degD[rn];
        float4 a0 = {0,0,0,0}, a1 = {0,0,0,0}, a2 = {0,0,0,0}, a3 = {0,0,0,0};
        int k = st;
        if (r < 6) {
            for (; k + 4 <= en; k += 4) {
                int s0 = esrc[k], s1 = esrc[k+1], s2 = esrc[k+2], s3 = esrc[k+3];
                ushort4 v0 = *reinterpret_cast<const ushort4*>(&xb[(size_t)s0 * F_IN]);
                ushort4 v1 = *reinterpret_cast<const ushort4*>(&xb[(size_t)s1 * F_IN]);
                ushort4 v2 = *reinterpret_cast<const ushort4*>(&xb[(size_t)s2 * F_IN]);
                ushort4 v3 = *reinterpret_cast<const ushort4*>(&xb[(size_t)s3 * F_IN]);
                a0.x += b2f(v0.x); a0.y += b2f(v0.y); a0.z += b2f(v0.z); a0.w += b2f(v0.w);
                a1.x += b2f(v1.x); a1.y += b2f(v1.y); a1.z += b2f(v1.z); a1.w += b2f(v1.w);
                a2.x += b2f(v2.x); a2.y += b2f(v2.y); a2.z += b2f(v2.z); a2.w += b2f(v2.w);
                a3.x += b2f(v3.x); a3.y += b2f(v3.y); a3.z += b2f(v3.z); a3.w += b2f(v3.w);
            }
            for (; k < en; ++k) {
                int s = esrc[k];
                ushort4 v = *reinterpret_cast<const ushort4*>(&xb[(size_t)s * F_IN]);
                a0.x += b2f(v.x); a0.y += b2f(v.y); a0.z += b2f(v.z); a0.w += b2f(v.w);
            }
        } else {
            const float* ds = disS + (size_t)r * NNODES;
            for (; k + 4 <= en; k += 4) {
                int s0 = esrc[k], s1 = esrc[k+1], s2 = esrc[k+2], s3 = esrc[k+3];
                ushort4 v0 = *reinterpret_cast<const ushort4*>(&xb[(size_t)s0 * F_IN]);
                ushort4 v1 = *reinterpret_cast<const ushort4*>(&xb[(size_t)s1 * F_IN]);
                ushort4 v2 = *reinterpret_cast<const ushort4*>(&xb[(size_t)s2 * F_IN]);
                ushort4 v3 = *reinterpret_cast<const ushort4*>(&xb[(size_t)s3 * F_IN]);
                float c0 = ds[s0], c1 = ds[s1], c2 = ds[s2], c3 = ds[s3];
                a0.x += b2f(v0.x)*c0; a0.y += b2f(v0.y)*c0; a0.z += b2f(v0.z)*c0; a0.w += b2f(v0.w)*c0;
                a1.x += b2f(v1.x)*c1; a1.y += b2f(v1.y)*c1; a1.z += b2f(v1.z)*c1; a1.w += b2f(v1.w)*c1;
                a2.x += b2f(v2.x)*c2; a2.y += b2f(v2.y)*c2; a2.z += b2f(v2.z)*c2; a2.w += b2f(v2.w)*c2;
                a3.x += b2f(v3.x)*c3; a3.y += b2f(v3.y)*c3; a3.z += b2f(v3.z)*c3; a3.w += b2f(v3.w)*c3;
            }
            for (; k < en; ++k) {
                int s = esrc[k];
                ushort4 v = *reinterpret_cast<const ushort4*>(&xb[(size_t)s * F_IN]);
                float cc = ds[s];
                a0.x += b2f(v.x)*cc; a0.y += b2f(v.y)*cc; a0.z += b2f(v.z)*cc; a0.w += b2f(v.w)*cc;
            }
            float dd = disD[rn];
            a0.x = a0.x*dd; a0.y = a0.y*dd; a0.z = a0.z*dd; a0.w = a0.w*dd;
            a1.x = a1.x*dd; a1.y = a1.y*dd; a1.z = a1.z*dd; a1.w = a1.w*dd;
            a2.x = a2.x*dd; a2.y = a2.y*dd; a2.z = a2.z*dd; a2.w = a2.w*dd;
            a3.x = a3.x*dd; a3.y = a3.y*dd; a3.z = a3.z*dd; a3.w = a3.w*dd;
        }
        float fx = a0.x + a1.x + a2.x + a3.x;
        float fy = a0.y + a1.y + a2.y + a3.y;
        float fz = a0.z + a1.z + a2.z + a3.z;
        float fw = a0.w + a1.w + a2.w + a3.w;
        ushort4 o; o.x = f2b(fx); o.y = f2b(fy); o.z = f2b(fz); o.w = f2b(fw);
        *reinterpret_cast<ushort4*>(&buf[(size_t)n * K1 + r * F_IN + lane * 4]) = o;
    }
}

// ---------------- layer-2 fused gather (4-way ILP, weight-first finish) ----------------
__global__ __launch_bounds__(256) void gather2_kernel(const ushort* __restrict__ T,
                                                      const int* __restrict__ esrc,
                                                      const int* __restrict__ offs,
                                                      const int* __restrict__ degD,
                                                      const float* __restrict__ disS,
                                                      const float* __restrict__ disD,
                                                      const float* __restrict__ bsum2,
                                                      float* __restrict__ out) {
    int lane = threadIdx.x & 31, grp = threadIdx.x >> 5;
    int n = blockIdx.x * 8 + grp;
    if (n >= NNODES) return;
    float4 acc = *reinterpret_cast<const float4*>(&bsum2[lane * 4]);
    for (int r = 0; r < NREL; ++r) {
        int rn = r * NNODES + n;
        int st = offs[rn], en = st + degD[rn];
        const float* ds = disS + (size_t)r * NNODES;
        const ushort* Tr = T + (size_t)r * F_OUT + lane * 4;
        float4 a0 = {0,0,0,0}, a1 = {0,0,0,0}, a2 = {0,0,0,0}, a3 = {0,0,0,0};
        int k = st;
        for (; k + 4 <= en; k += 4) {
            int s0 = esrc[k], s1 = esrc[k+1], s2 = esrc[k+2], s3 = esrc[k+3];
            ushort4 v0 = *reinterpret_cast<const ushort4*>(&Tr[(size_t)s0 * N2]);
            ushort4 v1 = *reinterpret_cast<const ushort4*>(&Tr[(size_t)s1 * N2]);
            ushort4 v2 = *reinterpret_cast<const ushort4*>(&Tr[(size_t)s2 * N2]);
            ushort4 v3 = *reinterpret_cast<const ushort4*>(&Tr[(size_t)s3 * N2]);
            float c0 = ds[s0], c1 = ds[s1], c2 = ds[s2], c3 = ds[s3];
            a0.x += b2f(v0.x)*c0; a0.y += b2f(v0.y)*c0; a0.z += b2f(v0.z)*c0; a0.w += b2f(v0.w)*c0;
            a1.x += b2f(v1.x)*c1; a1.y += b2f(v1.y)*c1; a1.z += b2f(v1.z)*c1; a1.w += b2f(v1.w)*c1;
            a2.x += b2f(v2.x)*c2; a2.y += b2f(v2.y)*c2; a2.z += b2f(v2.z)*c2; a2.w += b2f(v2.w)*c2;
            a3.x += b2f(v3.x)*c3; a3.y += b2f(v3.y)*c3; a3.z += b2f(v3.z)*c3; a3.w += b2f(v3.w)*c3;
        }
        for (; k < en; ++k) {
            int s = esrc[k];
            ushort4 v = *reinterpret_cast<const ushort4*>(&Tr[(size_t)s * N2]);
            float cc = ds[s];
            a0.x += b2f(v.x)*cc; a0.y += b2f(v.y)*cc; a0.z += b2f(v.z)*cc; a0.w += b2f(v.w)*cc;
        }
        float dd = disD[rn];
        acc.x += (a0.x + a1.x + a2.x + a3.x) * dd;
        acc.y += (a0.y + a1.y + a2.y + a3.y) * dd;
        acc.z += (a0.z + a1.z + a2.z + a3.z) * dd;
        acc.w += (a0.w + a1.w + a2.w + a3.w) * dd;
    }
    acc.x = acc.x > 0.f ? acc.x : 0.01f * acc.x;
    acc.y = acc.y > 0.f ? acc.y : 0.01f * acc.y;
    acc.z = acc.z > 0.f ? acc.z : 0.01f * acc.z;
    acc.w = acc.w > 0.f ? acc.w : 0.01f * acc.w;
    *reinterpret_cast<float4*>(&out[(size_t)n * F_OUT + lane * 4]) = acc;
}

// ---------------- bf16 MFMA GEMM (unchanged from R3) ----------------
template<int KDIM, int NOUT, bool EPI>
__global__ __launch_bounds__(256) void gemm_bf16(const ushort* __restrict__ A, int Astride,
                                                 const ushort* __restrict__ Bt, int Bstride,
                                                 ushort* __restrict__ C,
                                                 const float* __restrict__ bsum) {
    __shared__ ushort Al[128 * 64];
    __shared__ ushort Bl[128 * 64];
    const int tid = threadIdx.x;
    const int lane = tid & 63;
    const int w = tid >> 6;
    const int wm = w >> 1, wn = w & 1;
    const int m0 = blockIdx.x * 128, n0 = blockIdx.y * 128;

    const int r8 = lane >> 3;
    const int sl = (lane & 7) ^ r8;
    const char* Ab = (const char*)A + (size_t)(m0 + w * 32 + r8) * Astride + sl * 16;
    const char* Bb = (const char*)Bt + (size_t)(n0 + w * 32 + r8) * Bstride + sl * 16;

    f32x4 acc[4][4];
    #pragma unroll
    for (int i = 0; i < 4; ++i)
        #pragma unroll
        for (int j = 0; j < 4; ++j) acc[i][j] = (f32x4){0.f, 0.f, 0.f, 0.f};

    for (int kt = 0; kt < KDIM / 64; ++kt) {
        const size_t kb = (size_t)kt * 128;
        #pragma unroll
        for (int i = 0; i < 4; ++i) {
            gload16(Ab + (size_t)(i * 8) * Astride + kb, &Al[(w * 32 + i * 8) * 64]);
            gload16(Bb + (size_t)(i * 8) * Bstride + kb, &Bl[(w * 32 + i * 8) * 64]);
        }
        __syncthreads();
        bf16x8 a[2][4], b[2][4];
        #pragma unroll
        for (int ks = 0; ks < 2; ++ks) {
            #pragma unroll
            for (int m = 0; m < 4; ++m) {
                int row = wm * 64 + m * 16 + (lane & 15);
                int slot = (ks * 4 + (lane >> 4)) ^ (row & 7);
                a[ks][m] = *reinterpret_cast<const bf16x8*>(&Al[row * 64 + slot * 8]);
                int rowb = wn * 64 + m * 16 + (lane & 15);
                int slotb = (ks * 4 + (lane >> 4)) ^ (rowb & 7);
                b[ks][m] = *reinterpret_cast<const bf16x8*>(&Bl[rowb * 64 + slotb * 8]);
            }
        }
        #pragma unroll
        for (int ks = 0; ks < 2; ++ks)
            #pragma unroll
            for (int m = 0; m < 4; ++m)
                #pragma unroll
                for (int n = 0; n < 4; ++n)
                    acc[m][n] = __builtin_amdgcn_mfma_f32_16x16x32_bf16(a[ks][m], b[ks][n], acc[m][n], 0, 0, 0);
        __syncthreads();
    }
    #pragma unroll
    for (int m = 0; m < 4; ++m) {
        int rbase = m0 + wm * 64 + m * 16 + (lane >> 4) * 4;
        #pragma unroll
        for (int n = 0; n < 4; ++n) {
            int col = n0 + wn * 64 + n * 16 + (lane & 15);
            float bb = EPI ? bsum[col] : 0.f;
            #pragma unroll
            for (int q = 0; q < 4; ++q) {
                int r = rbase + q;
                if (r < NNODES) {
                    float v = acc[m][n][q];
                    if (EPI) { v += bb; v = v > 0.f ? v : 0.01f * v; }
                    C[(size_t)r * NOUT + col] = f2b(v);
                }
            }
        }
    }
}

extern "C" void kernel_launch(void* const* d_in, const int* in_sizes, int n_in,
                              void* d_out, int out_size, void* d_ws, size_t ws_size,
                              hipStream_t stream) {
    const float* x   = (const float*)d_in[0];
    const int*   src = (const int*)d_in[1];
    const int*   dst = (const int*)d_in[2];
    const float* W1  = (const float*)d_in[3];
    const float* b1  = (const float*)d_in[4];
    const float* W2  = (const float*)d_in[5];
    const float* b2  = (const float*)d_in[6];
    float* out = (float*)d_out;

    // ---- workspace layout ----
    char* p = (char*)d_ws;
    int*    cnt_d = (int*)p;    p += (size_t)NCHUNK * RN * sizeof(int);   // 14.4MB
    int*    cnt_s = (int*)p;    p += (size_t)NCHUNK * RN * sizeof(int);   // 14.4MB (aliased as cbase after sumdis)
    int*    degD  = (int*)p;    p += (size_t)RN * sizeof(int);
    float*  disS  = (float*)p;  p += (size_t)RN * sizeof(float);
    float*  disD  = (float*)p;  p += (size_t)RN * sizeof(float);
    int*    offs  = (int*)p;    p += (size_t)RN * sizeof(int);
    int*    bsums = (int*)p;    p += (size_t)1024 * sizeof(int);
    float*  bsum1 = (float*)p;  p += (size_t)512 * sizeof(float);
    float*  bsum2 = (float*)p;  p += (size_t)512 * sizeof(float);
    int*    esrc  = (int*)p;    p += (size_t)RE * sizeof(int);
    ushort* x_bf  = (ushort*)p; p += (size_t)NNODES * F_IN * sizeof(ushort);
    ushort* W1t   = (ushort*)p; p += (size_t)N1 * K1 * sizeof(ushort);
    ushort* W2t   = (ushort*)p; p += (size_t)N2 * K2 * sizeof(ushort);
    ushort* h1_bf = (ushort*)p; p += (size_t)MPAD * HID * sizeof(ushort);
    ushort* buf   = (ushort*)p; // [MPAD][K1] bf16 (115MB): AGG1, then T
    int* cbase = cnt_s;         // alias: cnt_s dead after sumdis_kernel

    dim3 hgrid(NCHUNK, NRANGE, NREL);

    // ---- CSR build: histogram -> scan -> fill (no global atomics) ----
    hist_kernel<<<hgrid, 256, 0, stream>>>(dst, cnt_d);
    hist_kernel<<<hgrid, 256, 0, stream>>>(src, cnt_s);
    sumdis_kernel<<<(RN + 255) / 256, 256, 0, stream>>>(cnt_s, cnt_d, degD, disS, disD);
    scanA_kernel<<<NBLK, 256, 0, stream>>>(degD, bsums);
    scanB_kernel<<<1, 512, 0, stream>>>(bsums);
    scanC_kernel<<<NBLK, 256, 0, stream>>>(degD, bsums, offs);
    chunkbase_kernel<<<(RN + 255) / 256, 256, 0, stream>>>(cnt_d, offs, cbase);
    fill2_kernel<<<hgrid, 256, 0, stream>>>(src, dst, cbase, esrc);

    // ---- precompute: bf16 conversions ----
    to_bf16_kernel<<<(NNODES * F_IN / 4 + 255) / 256, 256, 0, stream>>>(x, x_bf, NNODES * F_IN / 4);
    w1t_kernel<<<(NREL * F_IN * HID + 255) / 256, 256, 0, stream>>>(W1, W1t);
    w2t_kernel<<<(NREL * HID * F_OUT + 255) / 256, 256, 0, stream>>>(W2, W2t);
    bias_sum_kernel<<<1, 256, 0, stream>>>(b1, b2, bsum1, bsum2);

    // ---- layer 1: gather (aggregate-first, stacked) then one GEMM ----
    gather1_kernel<<<(NNODES + 7) / 8, 256, 0, stream>>>(x_bf, esrc, offs, degD,
                                                         disS, disD, buf);
    {
        dim3 g(MPAD / 128, N1 / 128);
        gemm_bf16<K1, N1, true><<<g, 256, 0, stream>>>(buf, K1 * 2, W1t, K1 * 2, h1_bf, bsum1);
    }

    // ---- layer 2: weight-first GEMM (T = h1 @ W2stack) then fused gather ----
    {
        dim3 g(MPAD / 128, N2 / 128);
        gemm_bf16<K2, N2, false><<<g, 256, 0, stream>>>(h1_bf, K2 * 2, W2t, K2 * 2, buf, nullptr);
    }
    gather2_kernel<<<(NNODES + 7) / 8, 256, 0, stream>>>(buf, esrc, offs, degD,
                                                         disS, disD, bsum2, out);
}